// Round 5
// baseline (22537.520 us; speedup 1.0000x reference)
//
#include <hip/hip_runtime.h>

// ---------------------------------------------------------------------------
// RAFT+DICL correlation module — fp32, register-tiled K-major convs, v2.
//  - conv1 split: f1-half computed once per batch image (shared across 81
//    displacements), sampled-half per displacement. corr holds only 32 ch.
//  - deconv: parity class = blockIdx.y -> wave-uniform scalar weights.
//  - TO=32 output channels per thread.
//  - chunk=27 preferred: keeps per-iteration working set L2/L3-resident.
// Input order is INTERLEAVED: d_in[0]=fmap1_0, d_in[1]=fmap2_0, ...
// ---------------------------------------------------------------------------

constexpr int D9 = 9, NB = 2, HH = 48, WW = 64;
constexpr int NIMG = NB * D9 * D9;       // 162
constexpr int HW = HH * WW;              // 3072
constexpr int H2 = 24, W2 = 32, HW2 = H2 * W2;  // 768

// K-major transposed weight sizes (per level)
constexpr int K1 = 576,  OC1 = 96;
constexpr int K2 = 864,  OC2 = 128;
constexpr int K3 = 1152, OC3 = 128;
constexpr int K4 = 1152, OC4 = 64;
constexpr int K5 = 256,  OC5 = 32;       // per parity class, 4 classes
constexpr int BT1 = 0;
constexpr int BT2 = BT1 + K1 * OC1;
constexpr int BT3 = BT2 + K2 * OC2;
constexpr int BT4 = BT3 + K3 * OC3;
constexpr int BT5 = BT4 + K4 * OC4;
constexpr int WL  = BT5 + 4 * K5 * OC5;  // floats per level

static inline int cdiv(int a, int b) { return (a + b - 1) / b; }

// ---------------- weight prep ----------------
__global__ void transpose_w(const float* __restrict__ w, float* __restrict__ wT,
                            int OC, int K, int dstStride)
{
    int idx = blockIdx.x * blockDim.x + threadIdx.x;
    int tot = 4 * OC * K;
    if (idx >= tot) return;
    int lvl = idx / (OC * K);
    int r = idx - lvl * OC * K;
    int oc = r / K;
    int k = r - oc * K;
    wT[(size_t)lvl * dstStride + (size_t)k * OC + oc] = w[idx];
}

__global__ void transpose_w5(const float* __restrict__ w5, float* __restrict__ wT5,
                             int dstStride)
{
    int idx = blockIdx.x * blockDim.x + threadIdx.x;
    if (idx >= 4 * 32 * 64 * 16) return;
    int t  = idx & 15;
    int ic = (idx >> 4) & 63;
    int oc = (idx >> 10) & 31;
    int lvl = idx >> 15;
    int ky = t >> 2, kx = t & 3;
    int p = ky & 1, u = ky >> 1, q = kx & 1, v = kx >> 1;
    wT5[(size_t)lvl * dstStride + (((p * 2 + q) * K5 + (ic * 4 + u * 2 + v)) * OC5 + oc)] = w5[idx];
}

// ---------------- sampling (sampled half only: 32 channels) ----------------
__global__ void sample_kernel(const float* __restrict__ f2,
                              const float* __restrict__ coords, float* __restrict__ corr,
                              int n0, int nimg, int h2, int w2, float inv_scale)
{
    int idx = blockIdx.x * blockDim.x + threadIdx.x;
    int total = nimg * HW;
    if (idx >= total) return;
    int x = idx % WW;
    int t = idx / WW;
    int y = t % HH;
    int nl = t / HH;
    int ng = n0 + nl;
    int b = ng / (D9 * D9);
    int c81 = ng % (D9 * D9);
    int di = c81 / D9;
    int dj = c81 % D9;

    float cx = coords[((size_t)(b * 2 + 0) * HH + y) * WW + x];
    float cy = coords[((size_t)(b * 2 + 1) * HH + y) * WW + x];
    float gx = cx * inv_scale + (float)(di - 4);
    float gy = cy * inv_scale + (float)(dj - 4);

    float x0f = floorf(gx), y0f = floorf(gy);
    float wx = gx - x0f, wy = gy - y0f;
    int x0 = (int)x0f, y0 = (int)y0f;
    int x1 = x0 + 1, y1 = y0 + 1;
    bool vx0 = (x0 >= 0) && (x0 <= w2 - 1);
    bool vx1 = (x1 >= 0) && (x1 <= w2 - 1);
    bool vy0 = (y0 >= 0) && (y0 <= h2 - 1);
    bool vy1 = (y1 >= 0) && (y1 <= h2 - 1);
    int xc0 = min(max(x0, 0), w2 - 1), xc1 = min(max(x1, 0), w2 - 1);
    int yc0 = min(max(y0, 0), h2 - 1), yc1 = min(max(y1, 0), h2 - 1);
    float m00 = (vx0 && vy0) ? (1.f - wx) * (1.f - wy) : 0.f;
    float m10 = (vx1 && vy0) ? wx * (1.f - wy) : 0.f;
    float m01 = (vx0 && vy1) ? (1.f - wx) * wy : 0.f;
    float m11 = (vx1 && vy1) ? wx * wy : 0.f;

    const float* f2b = f2 + (size_t)b * 32 * h2 * w2;
    float* outb = corr + (size_t)nl * 32 * HW + (size_t)y * WW + x;

    int o00 = yc0 * w2 + xc0, o10 = yc0 * w2 + xc1;
    int o01 = yc1 * w2 + xc0, o11 = yc1 * w2 + xc1;
    #pragma unroll 4
    for (int ch = 0; ch < 32; ++ch) {
        const float* im = f2b + (size_t)ch * h2 * w2;
        float v = m00 * im[o00] + m10 * im[o10] + m01 * im[o01] + m11 * im[o11];
        outb[(size_t)ch * HW] = v;
    }
}

// ---------------- K-major register-tiled conv3x3 ----------------
// Weights wT: [K=IC*9][OC], block-uniform address -> scalar loads.
// One thread: 1 output pixel x TO=32 output channels.
// PART: accumulator initialized from precomputed partial (conv1 f1-half,
//       shared across the 81 displacement images of a batch image).
template <int IC, int OC, int IH, int IW, int OH, int OW, int S, bool RELU, bool PART>
__global__ __launch_bounds__(256)
void conv_km(const float* __restrict__ in, const float* __restrict__ wT,
             const float* __restrict__ bias, float* __restrict__ out,
             const float* __restrict__ part, int n0)
{
    constexpr int TO = 32;
    constexpr int BR = 256 / OW;
    int tx = threadIdx.x;
    int ox = tx % OW;
    int oy = blockIdx.x * BR + tx / OW;
    int oc0 = blockIdx.y * TO;
    int n = blockIdx.z;

    float acc[TO];
    if (PART) {
        int bimg = (n0 + n) / (D9 * D9);
        const float* pp = part + ((size_t)(bimg * OC) + oc0) * (OH * OW) + oy * OW + ox;
        #pragma unroll
        for (int o = 0; o < TO; ++o) acc[o] = pp[(size_t)o * OH * OW];
    } else {
        #pragma unroll
        for (int o = 0; o < TO; ++o) acc[o] = bias[oc0 + o];
    }

    int cx = ox * S, cy = oy * S;
    bool mL = (cx - 1 >= 0), mR = (cx + 1 < IW);
    int xl = mL ? cx - 1 : 0, xr = mR ? cx + 1 : IW - 1;

    const float* ip = in + (size_t)n * IC * IH * IW;
    const float* wk = wT + oc0;

    for (int ic = 0; ic < IC; ++ic) {
        const float* icp = ip + ic * IH * IW;
        const float* wpk = wk + ic * 9 * OC;
        #pragma unroll
        for (int ky = 0; ky < 3; ++ky) {
            int iy = cy + ky - 1;
            if ((unsigned)iy < (unsigned)IH) {
                const float* rp = icp + iy * IW;
                float v0 = rp[xl]; v0 = mL ? v0 : 0.f;
                float v1 = rp[cx];
                float v2 = rp[xr]; v2 = mR ? v2 : 0.f;
                const float* wp = wpk + ky * 3 * OC;
                #pragma unroll
                for (int o = 0; o < TO; ++o) acc[o] = fmaf(v0, wp[o], acc[o]);
                #pragma unroll
                for (int o = 0; o < TO; ++o) acc[o] = fmaf(v1, wp[OC + o], acc[o]);
                #pragma unroll
                for (int o = 0; o < TO; ++o) acc[o] = fmaf(v2, wp[2 * OC + o], acc[o]);
            }
        }
    }
    float* ob = out + ((size_t)n * OC + oc0) * OH * OW + oy * OW + ox;
    #pragma unroll
    for (int o = 0; o < TO; ++o) {
        float r = acc[o];
        if (RELU) r = fmaxf(r, 0.f);
        ob[(size_t)o * OH * OW] = r;
    }
}

// ---------------- deconv (parity class = blockIdx.y -> scalar weights) -----
__global__ __launch_bounds__(256)
void deconv_km(const float* __restrict__ in, const float* __restrict__ wT5,
               const float* __restrict__ bias, float* __restrict__ out)
{
    int tx = threadIdx.x;
    int cls = blockIdx.y;
    int p = cls >> 1, q = cls & 1;
    int a = blockIdx.x * 8 + (tx >> 5);   // 0..23
    int b = tx & 31;                      // 0..31
    int n = blockIdx.z;

    float acc[32];
    #pragma unroll
    for (int o = 0; o < 32; ++o) acc[o] = bias[o];

    int iy0 = a + p - 1, iy1 = a + p;
    int ix0 = b + q - 1, ix1 = b + q;
    bool my0 = iy0 >= 0, my1 = iy1 <= H2 - 1, mx0 = ix0 >= 0, mx1 = ix1 <= W2 - 1;
    int cy0 = my0 ? iy0 : 0, cy1 = my1 ? iy1 : H2 - 1;
    int cx0 = mx0 ? ix0 : 0, cx1 = mx1 ? ix1 : W2 - 1;

    const float* ib = in + (size_t)n * 64 * HW2;
    const float* wc = wT5 + (size_t)cls * K5 * OC5;

    for (int ic = 0; ic < 64; ++ic) {
        const float* icp = ib + ic * HW2;
        float v00 = icp[cy0 * W2 + cx0]; v00 = (my0 && mx0) ? v00 : 0.f;
        float v01 = icp[cy0 * W2 + cx1]; v01 = (my0 && mx1) ? v01 : 0.f;
        float v10 = icp[cy1 * W2 + cx0]; v10 = (my1 && mx0) ? v10 : 0.f;
        float v11 = icp[cy1 * W2 + cx1]; v11 = (my1 && mx1) ? v11 : 0.f;
        const float* wp = wc + ic * 4 * OC5;
        #pragma unroll
        for (int o = 0; o < 32; ++o) acc[o] = fmaf(v00, wp[o], acc[o]);
        #pragma unroll
        for (int o = 0; o < 32; ++o) acc[o] = fmaf(v01, wp[OC5 + o], acc[o]);
        #pragma unroll
        for (int o = 0; o < 32; ++o) acc[o] = fmaf(v10, wp[2 * OC5 + o], acc[o]);
        #pragma unroll
        for (int o = 0; o < 32; ++o) acc[o] = fmaf(v11, wp[3 * OC5 + o], acc[o]);
    }
    int oy = 2 * a + p, ox = 2 * b + q;
    float* ob = out + ((size_t)n * 32) * HW + oy * WW + ox;
    #pragma unroll
    for (int o = 0; o < 32; ++o) ob[(size_t)o * HW] = fmaxf(acc[o], 0.f);
}

// ---------------- conv6 (32->1) ----------------
__global__ void conv6_kernel(const float* __restrict__ in, const float* __restrict__ w6,
                             const float* __restrict__ b6, float* __restrict__ cost,
                             int n0, int nimg)
{
    int idx = blockIdx.x * blockDim.x + threadIdx.x;
    if (idx >= nimg * HW) return;
    int x = idx % WW;
    int t = idx / WW;
    int y = t % HH;
    int nl = t / HH;
    float acc = b6[0];
    const float* ib = in + (size_t)nl * 32 * HW;
    bool mL = x >= 1, mR = x + 1 < WW;
    int xl = mL ? x - 1 : 0, xr = mR ? x + 1 : WW - 1;
    for (int ic = 0; ic < 32; ++ic) {
        const float* icp = ib + ic * HW;
        #pragma unroll
        for (int ky = 0; ky < 3; ++ky) {
            int iy = y + ky - 1;
            if ((unsigned)iy < (unsigned)HH) {
                const float* rp = icp + iy * WW;
                float v0 = rp[xl]; v0 = mL ? v0 : 0.f;
                float v1 = rp[x];
                float v2 = rp[xr]; v2 = mR ? v2 : 0.f;
                const float* wp = w6 + ic * 9 + ky * 3;
                acc = fmaf(v0, wp[0], acc);
                acc = fmaf(v1, wp[1], acc);
                acc = fmaf(v2, wp[2], acc);
            }
        }
    }
    cost[(size_t)(n0 + nl) * HW + y * WW + x] = acc;
}

// ---------------- DAP ----------------
__global__ void dap_kernel(const float* __restrict__ cost, const float* __restrict__ dapw,
                           float* __restrict__ out, int lvl)
{
    int idx = blockIdx.x * blockDim.x + threadIdx.x;
    int total = NB * 81 * HW;
    if (idx >= total) return;
    int px = idx % HW;
    int t = idx / HW;
    int o = t % 81;
    int b = t / 81;
    const float* dw = dapw + (size_t)o * 81;
    const float* cb = cost + (size_t)b * 81 * HW + px;
    float acc = 0.f;
    #pragma unroll 9
    for (int c = 0; c < 81; ++c) acc = fmaf(dw[c], cb[(size_t)c * HW], acc);
    out[((size_t)(b * 4 * 81 + lvl * 81 + o)) * HW + px] = acc;
}

// ---------------------------------------------------------------------------
extern "C" void kernel_launch(void* const* d_in, const int* in_sizes, int n_in,
                              void* d_out, int out_size, void* d_ws, size_t ws_size,
                              hipStream_t stream)
{
    const float* f1[4] = {(const float*)d_in[0], (const float*)d_in[2],
                          (const float*)d_in[4], (const float*)d_in[6]};
    const float* f2[4] = {(const float*)d_in[1], (const float*)d_in[3],
                          (const float*)d_in[5], (const float*)d_in[7]};
    const float* coords = (const float*)d_in[8];
    const float* mw1 = (const float*)d_in[9];
    const float* mb1 = (const float*)d_in[10];
    const float* mw2 = (const float*)d_in[11];
    const float* mb2 = (const float*)d_in[12];
    const float* mw3 = (const float*)d_in[13];
    const float* mb3 = (const float*)d_in[14];
    const float* mw4 = (const float*)d_in[15];
    const float* mb4 = (const float*)d_in[16];
    const float* mw5 = (const float*)d_in[17];
    const float* mb5 = (const float*)d_in[18];
    const float* mw6 = (const float*)d_in[19];
    const float* mb6 = (const float*)d_in[20];
    const float* dapw = (const float*)d_in[21];
    float* out = (float*)d_out;

    // ws layout: weights | cost | part | bufA | bufB
    const size_t wBytes = ((size_t)4 * WL * 4 + 255) / 256 * 256;
    const size_t costBytes = ((size_t)NIMG * HW * 4 + 255) / 256 * 256;
    const size_t partBytes = ((size_t)NB * 96 * HW * 4 + 255) / 256 * 256;
    const size_t SA = (size_t)32 * HW * 4;    // corr(32ch) / x2 / x4
    const size_t SB = (size_t)96 * HW * 4;    // x1 / x3 / x5

    static const int divs[11] = {27, 54, 18, 9, 81, 6, 162, 3, 2, 1, 1};
    int chunk = 1;
    for (int i = 0; i < 11; ++i) {
        size_t need = wBytes + costBytes + partBytes + (size_t)divs[i] * (SA + SB) + 1024;
        if (need <= ws_size) { chunk = divs[i]; break; }
    }

    char* wsb = (char*)d_ws;
    float* wsW = (float*)wsb;
    float* cost = (float*)(wsb + wBytes);
    float* part = (float*)(wsb + wBytes + costBytes);
    float* bufA = (float*)(wsb + wBytes + costBytes + partBytes);
    float* bufB = (float*)(wsb + wBytes + costBytes + partBytes + (size_t)chunk * SA);

    const int TPB = 256;

    transpose_w<<<cdiv(4 * OC1 * K1, TPB), TPB, 0, stream>>>(mw1, wsW + BT1, OC1, K1, WL);
    transpose_w<<<cdiv(4 * OC2 * K2, TPB), TPB, 0, stream>>>(mw2, wsW + BT2, OC2, K2, WL);
    transpose_w<<<cdiv(4 * OC3 * K3, TPB), TPB, 0, stream>>>(mw3, wsW + BT3, OC3, K3, WL);
    transpose_w<<<cdiv(4 * OC4 * K4, TPB), TPB, 0, stream>>>(mw4, wsW + BT4, OC4, K4, WL);
    transpose_w5<<<cdiv(4 * 32 * 64 * 16, TPB), TPB, 0, stream>>>(mw5, wsW + BT5, WL);

    for (int lvl = 0; lvl < 4; ++lvl) {
        int h2 = HH >> lvl, w2 = WW >> lvl;
        float inv_scale = 1.0f / (float)(1 << lvl);
        const float* wT = wsW + (size_t)lvl * WL;
        const float* b1 = mb1 + (size_t)lvl * 96;
        const float* b2 = mb2 + (size_t)lvl * 128;
        const float* b3 = mb3 + (size_t)lvl * 128;
        const float* b4 = mb4 + (size_t)lvl * 64;
        const float* b5 = mb5 + (size_t)lvl * 32;
        const float* w6 = mw6 + (size_t)lvl * 288;
        const float* b6 = mb6 + (size_t)lvl * 1;

        // conv1 f1-half, shared across displacements: [2 imgs, 32ch] -> part[2][96][3072]
        // (bias included, NO relu — relu applies after adding the sampled half)
        conv_km<32, 96, 48, 64, 48, 64, 1, false, false><<<dim3(12, 3, 2), TPB, 0, stream>>>(
            f1[lvl], wT + BT1, b1, part, nullptr, 0);

        for (int n0 = 0; n0 < NIMG; n0 += chunk) {
            int n = chunk;
            sample_kernel<<<cdiv(n * HW, TPB), TPB, 0, stream>>>(
                f2[lvl], coords, bufA, n0, n, h2, w2, inv_scale);
            // conv1 sampled-half + partial, relu: A -> B   (ic 32..63 -> K rows 288..575)
            conv_km<32, 96, 48, 64, 48, 64, 1, true, true><<<dim3(12, 3, n), TPB, 0, stream>>>(
                bufA, wT + BT1 + 288 * OC1, b1, bufB, part, n0);
            // conv2 96->128 s2 relu: B -> A
            conv_km<96, 128, 48, 64, 24, 32, 2, true, false><<<dim3(3, 4, n), TPB, 0, stream>>>(
                bufB, wT + BT2, b2, bufA, nullptr, 0);
            // conv3 128->128 relu: A -> B
            conv_km<128, 128, 24, 32, 24, 32, 1, true, false><<<dim3(3, 4, n), TPB, 0, stream>>>(
                bufA, wT + BT3, b3, bufB, nullptr, 0);
            // conv4 128->64 relu: B -> A
            conv_km<128, 64, 24, 32, 24, 32, 1, true, false><<<dim3(3, 2, n), TPB, 0, stream>>>(
                bufB, wT + BT4, b4, bufA, nullptr, 0);
            // deconv 64->32 relu: A -> B
            deconv_km<<<dim3(3, 4, n), TPB, 0, stream>>>(bufA, wT + BT5, b5, bufB);
            // conv6 32->1: B -> cost
            conv6_kernel<<<cdiv(n * HW, TPB), TPB, 0, stream>>>(bufB, w6, b6, cost, n0, n);
        }
        dap_kernel<<<cdiv(NB * 81 * HW, TPB), TPB, 0, stream>>>(
            cost, dapw + (size_t)lvl * 81 * 81, out, lvl);
    }
}

// Round 9
// 7789.919 us; speedup vs baseline: 2.8932x; 2.8932x over previous
//
#include <hip/hip_runtime.h>

// ---------------------------------------------------------------------------
// RAFT+DICL correlation module — fp32, register-tiled K-major convs, v3.
//  - TO=16 output channels/thread (proven 24-VGPR codegen, round 3).
//  - chunk=81: working set L3-resident AND grids ~2000 blocks (occupancy).
//  - conv1 split: f1-half once per batch image; sampled-half per displacement.
//  - deconv: parity class + oc-half from blockIdx.y -> wave-uniform weights.
// Input order is INTERLEAVED: d_in[0]=fmap1_0, d_in[1]=fmap2_0, ...
// ---------------------------------------------------------------------------

constexpr int D9 = 9, NB = 2, HH = 48, WW = 64;
constexpr int NIMG = NB * D9 * D9;       // 162
constexpr int HW = HH * WW;              // 3072
constexpr int H2 = 24, W2 = 32, HW2 = H2 * W2;  // 768

// K-major transposed weight sizes (per level)
constexpr int K1 = 576,  OC1 = 96;
constexpr int K2 = 864,  OC2 = 128;
constexpr int K3 = 1152, OC3 = 128;
constexpr int K4 = 1152, OC4 = 64;
constexpr int K5 = 256,  OC5 = 32;       // per parity class, 4 classes
constexpr int BT1 = 0;
constexpr int BT2 = BT1 + K1 * OC1;
constexpr int BT3 = BT2 + K2 * OC2;
constexpr int BT4 = BT3 + K3 * OC3;
constexpr int BT5 = BT4 + K4 * OC4;
constexpr int WL  = BT5 + 4 * K5 * OC5;  // floats per level

static inline int cdiv(int a, int b) { return (a + b - 1) / b; }

// ---------------- weight prep ----------------
__global__ void transpose_w(const float* __restrict__ w, float* __restrict__ wT,
                            int OC, int K, int dstStride)
{
    int idx = blockIdx.x * blockDim.x + threadIdx.x;
    int tot = 4 * OC * K;
    if (idx >= tot) return;
    int lvl = idx / (OC * K);
    int r = idx - lvl * OC * K;
    int oc = r / K;
    int k = r - oc * K;
    wT[(size_t)lvl * dstStride + (size_t)k * OC + oc] = w[idx];
}

__global__ void transpose_w5(const float* __restrict__ w5, float* __restrict__ wT5,
                             int dstStride)
{
    int idx = blockIdx.x * blockDim.x + threadIdx.x;
    if (idx >= 4 * 32 * 64 * 16) return;
    int t  = idx & 15;
    int ic = (idx >> 4) & 63;
    int oc = (idx >> 10) & 31;
    int lvl = idx >> 15;
    int ky = t >> 2, kx = t & 3;
    int p = ky & 1, u = ky >> 1, q = kx & 1, v = kx >> 1;
    wT5[(size_t)lvl * dstStride + (((p * 2 + q) * K5 + (ic * 4 + u * 2 + v)) * OC5 + oc)] = w5[idx];
}

// ---------------- sampling (sampled half only: 32 channels) ----------------
__global__ void sample_kernel(const float* __restrict__ f2,
                              const float* __restrict__ coords, float* __restrict__ corr,
                              int n0, int nimg, int h2, int w2, float inv_scale)
{
    int idx = blockIdx.x * blockDim.x + threadIdx.x;
    int total = nimg * HW;
    if (idx >= total) return;
    int x = idx % WW;
    int t = idx / WW;
    int y = t % HH;
    int nl = t / HH;
    int ng = n0 + nl;
    int b = ng / (D9 * D9);
    int c81 = ng % (D9 * D9);
    int di = c81 / D9;
    int dj = c81 % D9;

    float cx = coords[((size_t)(b * 2 + 0) * HH + y) * WW + x];
    float cy = coords[((size_t)(b * 2 + 1) * HH + y) * WW + x];
    float gx = cx * inv_scale + (float)(di - 4);
    float gy = cy * inv_scale + (float)(dj - 4);

    float x0f = floorf(gx), y0f = floorf(gy);
    float wx = gx - x0f, wy = gy - y0f;
    int x0 = (int)x0f, y0 = (int)y0f;
    int x1 = x0 + 1, y1 = y0 + 1;
    bool vx0 = (x0 >= 0) && (x0 <= w2 - 1);
    bool vx1 = (x1 >= 0) && (x1 <= w2 - 1);
    bool vy0 = (y0 >= 0) && (y0 <= h2 - 1);
    bool vy1 = (y1 >= 0) && (y1 <= h2 - 1);
    int xc0 = min(max(x0, 0), w2 - 1), xc1 = min(max(x1, 0), w2 - 1);
    int yc0 = min(max(y0, 0), h2 - 1), yc1 = min(max(y1, 0), h2 - 1);
    float m00 = (vx0 && vy0) ? (1.f - wx) * (1.f - wy) : 0.f;
    float m10 = (vx1 && vy0) ? wx * (1.f - wy) : 0.f;
    float m01 = (vx0 && vy1) ? (1.f - wx) * wy : 0.f;
    float m11 = (vx1 && vy1) ? wx * wy : 0.f;

    const float* f2b = f2 + (size_t)b * 32 * h2 * w2;
    float* outb = corr + (size_t)nl * 32 * HW + (size_t)y * WW + x;

    int o00 = yc0 * w2 + xc0, o10 = yc0 * w2 + xc1;
    int o01 = yc1 * w2 + xc0, o11 = yc1 * w2 + xc1;
    #pragma unroll 4
    for (int ch = 0; ch < 32; ++ch) {
        const float* im = f2b + (size_t)ch * h2 * w2;
        float v = m00 * im[o00] + m10 * im[o10] + m01 * im[o01] + m11 * im[o11];
        outb[(size_t)ch * HW] = v;
    }
}

// ---------------- K-major register-tiled conv3x3 (TO=16) ----------------
// Weights wT: [K=IC*9][OC], block-uniform address -> scalar loads.
// One thread: 1 output pixel x 16 output channels.
// PART: accumulator initialized from precomputed partial (conv1 f1-half).
template <int IC, int OC, int IH, int IW, int OH, int OW, int S, bool RELU, bool PART>
__global__ __launch_bounds__(256)
void conv_km(const float* __restrict__ in, const float* __restrict__ wT,
             const float* __restrict__ bias, float* __restrict__ out,
             const float* __restrict__ part, int n0)
{
    constexpr int TO = 16;
    constexpr int BR = 256 / OW;
    int tx = threadIdx.x;
    int ox = tx % OW;
    int oy = blockIdx.x * BR + tx / OW;
    int oc0 = blockIdx.y * TO;
    int n = blockIdx.z;

    float acc[TO];
    if (PART) {
        int bimg = (n0 + n) / (D9 * D9);
        const float* pp = part + ((size_t)(bimg * OC) + oc0) * (OH * OW) + oy * OW + ox;
        #pragma unroll
        for (int o = 0; o < TO; ++o) acc[o] = pp[(size_t)o * OH * OW];
    } else {
        #pragma unroll
        for (int o = 0; o < TO; ++o) acc[o] = bias[oc0 + o];
    }

    int cx = ox * S, cy = oy * S;
    bool mL = (cx - 1 >= 0), mR = (cx + 1 < IW);
    int xl = mL ? cx - 1 : 0, xr = mR ? cx + 1 : IW - 1;

    const float* ip = in + (size_t)n * IC * IH * IW;
    const float* wk = wT + oc0;

    for (int ic = 0; ic < IC; ++ic) {
        const float* icp = ip + ic * IH * IW;
        const float* wpk = wk + ic * 9 * OC;
        #pragma unroll
        for (int ky = 0; ky < 3; ++ky) {
            int iy = cy + ky - 1;
            if ((unsigned)iy < (unsigned)IH) {
                const float* rp = icp + iy * IW;
                float v0 = rp[xl]; v0 = mL ? v0 : 0.f;
                float v1 = rp[cx];
                float v2 = rp[xr]; v2 = mR ? v2 : 0.f;
                const float* wp = wpk + ky * 3 * OC;
                #pragma unroll
                for (int o = 0; o < TO; ++o) acc[o] = fmaf(v0, wp[o], acc[o]);
                #pragma unroll
                for (int o = 0; o < TO; ++o) acc[o] = fmaf(v1, wp[OC + o], acc[o]);
                #pragma unroll
                for (int o = 0; o < TO; ++o) acc[o] = fmaf(v2, wp[2 * OC + o], acc[o]);
            }
        }
    }
    float* ob = out + ((size_t)n * OC + oc0) * OH * OW + oy * OW + ox;
    #pragma unroll
    for (int o = 0; o < TO; ++o) {
        float r = acc[o];
        if (RELU) r = fmaxf(r, 0.f);
        ob[(size_t)o * OH * OW] = r;
    }
}

// ---------------- deconv (TO=16; parity class + oc-half = blockIdx.y) ------
__global__ __launch_bounds__(256)
void deconv_km(const float* __restrict__ in, const float* __restrict__ wT5,
               const float* __restrict__ bias, float* __restrict__ out)
{
    constexpr int TO = 16;
    int tx = threadIdx.x;
    int cls = blockIdx.y >> 1;            // parity class 0..3
    int oc0 = (blockIdx.y & 1) * TO;      // 0 or 16
    int p = cls >> 1, q = cls & 1;
    int a = blockIdx.x * 8 + (tx >> 5);   // 0..23
    int b = tx & 31;                      // 0..31
    int n = blockIdx.z;

    float acc[TO];
    #pragma unroll
    for (int o = 0; o < TO; ++o) acc[o] = bias[oc0 + o];

    int iy0 = a + p - 1, iy1 = a + p;
    int ix0 = b + q - 1, ix1 = b + q;
    bool my0 = iy0 >= 0, my1 = iy1 <= H2 - 1, mx0 = ix0 >= 0, mx1 = ix1 <= W2 - 1;
    int cy0 = my0 ? iy0 : 0, cy1 = my1 ? iy1 : H2 - 1;
    int cx0 = mx0 ? ix0 : 0, cx1 = mx1 ? ix1 : W2 - 1;

    const float* ib = in + (size_t)n * 64 * HW2;
    const float* wc = wT5 + (size_t)cls * K5 * OC5 + oc0;

    for (int ic = 0; ic < 64; ++ic) {
        const float* icp = ib + ic * HW2;
        float v00 = icp[cy0 * W2 + cx0]; v00 = (my0 && mx0) ? v00 : 0.f;
        float v01 = icp[cy0 * W2 + cx1]; v01 = (my0 && mx1) ? v01 : 0.f;
        float v10 = icp[cy1 * W2 + cx0]; v10 = (my1 && mx0) ? v10 : 0.f;
        float v11 = icp[cy1 * W2 + cx1]; v11 = (my1 && mx1) ? v11 : 0.f;
        const float* wp = wc + ic * 4 * OC5;
        #pragma unroll
        for (int o = 0; o < TO; ++o) acc[o] = fmaf(v00, wp[o], acc[o]);
        #pragma unroll
        for (int o = 0; o < TO; ++o) acc[o] = fmaf(v01, wp[OC5 + o], acc[o]);
        #pragma unroll
        for (int o = 0; o < TO; ++o) acc[o] = fmaf(v10, wp[2 * OC5 + o], acc[o]);
        #pragma unroll
        for (int o = 0; o < TO; ++o) acc[o] = fmaf(v11, wp[3 * OC5 + o], acc[o]);
    }
    int oy = 2 * a + p, ox = 2 * b + q;
    float* ob = out + ((size_t)n * 32 + oc0) * HW + oy * WW + ox;
    #pragma unroll
    for (int o = 0; o < TO; ++o) ob[(size_t)o * HW] = fmaxf(acc[o], 0.f);
}

// ---------------- conv6 (32->1) ----------------
__global__ void conv6_kernel(const float* __restrict__ in, const float* __restrict__ w6,
                             const float* __restrict__ b6, float* __restrict__ cost,
                             int n0, int nimg)
{
    int idx = blockIdx.x * blockDim.x + threadIdx.x;
    if (idx >= nimg * HW) return;
    int x = idx % WW;
    int t = idx / WW;
    int y = t % HH;
    int nl = t / HH;
    float acc = b6[0];
    const float* ib = in + (size_t)nl * 32 * HW;
    bool mL = x >= 1, mR = x + 1 < WW;
    int xl = mL ? x - 1 : 0, xr = mR ? x + 1 : WW - 1;
    for (int ic = 0; ic < 32; ++ic) {
        const float* icp = ib + ic * HW;
        #pragma unroll
        for (int ky = 0; ky < 3; ++ky) {
            int iy = y + ky - 1;
            if ((unsigned)iy < (unsigned)HH) {
                const float* rp = icp + iy * WW;
                float v0 = rp[xl]; v0 = mL ? v0 : 0.f;
                float v1 = rp[x];
                float v2 = rp[xr]; v2 = mR ? v2 : 0.f;
                const float* wp = w6 + ic * 9 + ky * 3;
                acc = fmaf(v0, wp[0], acc);
                acc = fmaf(v1, wp[1], acc);
                acc = fmaf(v2, wp[2], acc);
            }
        }
    }
    cost[(size_t)(n0 + nl) * HW + y * WW + x] = acc;
}

// ---------------- DAP ----------------
__global__ void dap_kernel(const float* __restrict__ cost, const float* __restrict__ dapw,
                           float* __restrict__ out, int lvl)
{
    int idx = blockIdx.x * blockDim.x + threadIdx.x;
    int total = NB * 81 * HW;
    if (idx >= total) return;
    int px = idx % HW;
    int t = idx / HW;
    int o = t % 81;
    int b = t / 81;
    const float* dw = dapw + (size_t)o * 81;
    const float* cb = cost + (size_t)b * 81 * HW + px;
    float acc = 0.f;
    #pragma unroll 9
    for (int c = 0; c < 81; ++c) acc = fmaf(dw[c], cb[(size_t)c * HW], acc);
    out[((size_t)(b * 4 * 81 + lvl * 81 + o)) * HW + px] = acc;
}

// ---------------------------------------------------------------------------
extern "C" void kernel_launch(void* const* d_in, const int* in_sizes, int n_in,
                              void* d_out, int out_size, void* d_ws, size_t ws_size,
                              hipStream_t stream)
{
    const float* f1[4] = {(const float*)d_in[0], (const float*)d_in[2],
                          (const float*)d_in[4], (const float*)d_in[6]};
    const float* f2[4] = {(const float*)d_in[1], (const float*)d_in[3],
                          (const float*)d_in[5], (const float*)d_in[7]};
    const float* coords = (const float*)d_in[8];
    const float* mw1 = (const float*)d_in[9];
    const float* mb1 = (const float*)d_in[10];
    const float* mw2 = (const float*)d_in[11];
    const float* mb2 = (const float*)d_in[12];
    const float* mw3 = (const float*)d_in[13];
    const float* mb3 = (const float*)d_in[14];
    const float* mw4 = (const float*)d_in[15];
    const float* mb4 = (const float*)d_in[16];
    const float* mw5 = (const float*)d_in[17];
    const float* mb5 = (const float*)d_in[18];
    const float* mw6 = (const float*)d_in[19];
    const float* mb6 = (const float*)d_in[20];
    const float* dapw = (const float*)d_in[21];
    float* out = (float*)d_out;

    // ws layout: weights | cost | part | bufA | bufB
    const size_t wBytes = ((size_t)4 * WL * 4 + 255) / 256 * 256;
    const size_t costBytes = ((size_t)NIMG * HW * 4 + 255) / 256 * 256;
    const size_t partBytes = ((size_t)NB * 96 * HW * 4 + 255) / 256 * 256;
    const size_t SA = (size_t)32 * HW * 4;    // corr(32ch) / x2 / x4
    const size_t SB = (size_t)96 * HW * 4;    // x1 / x3 / x5

    // chunk=81 first: grids ~2000 blocks AND inter-stage working set (~130MB)
    // stays L3-resident. (chunk=27 collapsed occupancy in round 5.)
    static const int divs[10] = {81, 54, 27, 18, 162, 9, 6, 3, 2, 1};
    int chunk = 1;
    for (int i = 0; i < 10; ++i) {
        size_t need = wBytes + costBytes + partBytes + (size_t)divs[i] * (SA + SB) + 1024;
        if (need <= ws_size) { chunk = divs[i]; break; }
    }

    char* wsb = (char*)d_ws;
    float* wsW = (float*)wsb;
    float* cost = (float*)(wsb + wBytes);
    float* part = (float*)(wsb + wBytes + costBytes);
    float* bufA = (float*)(wsb + wBytes + costBytes + partBytes);
    float* bufB = (float*)(wsb + wBytes + costBytes + partBytes + (size_t)chunk * SA);

    const int TPB = 256;

    transpose_w<<<cdiv(4 * OC1 * K1, TPB), TPB, 0, stream>>>(mw1, wsW + BT1, OC1, K1, WL);
    transpose_w<<<cdiv(4 * OC2 * K2, TPB), TPB, 0, stream>>>(mw2, wsW + BT2, OC2, K2, WL);
    transpose_w<<<cdiv(4 * OC3 * K3, TPB), TPB, 0, stream>>>(mw3, wsW + BT3, OC3, K3, WL);
    transpose_w<<<cdiv(4 * OC4 * K4, TPB), TPB, 0, stream>>>(mw4, wsW + BT4, OC4, K4, WL);
    transpose_w5<<<cdiv(4 * 32 * 64 * 16, TPB), TPB, 0, stream>>>(mw5, wsW + BT5, WL);

    for (int lvl = 0; lvl < 4; ++lvl) {
        int h2 = HH >> lvl, w2 = WW >> lvl;
        float inv_scale = 1.0f / (float)(1 << lvl);
        const float* wT = wsW + (size_t)lvl * WL;
        const float* b1 = mb1 + (size_t)lvl * 96;
        const float* b2 = mb2 + (size_t)lvl * 128;
        const float* b3 = mb3 + (size_t)lvl * 128;
        const float* b4 = mb4 + (size_t)lvl * 64;
        const float* b5 = mb5 + (size_t)lvl * 32;
        const float* w6 = mw6 + (size_t)lvl * 288;
        const float* b6 = mb6 + (size_t)lvl * 1;

        // conv1 f1-half, shared across displacements: bias included, NO relu.
        conv_km<32, 96, 48, 64, 48, 64, 1, false, false><<<dim3(12, 6, 2), TPB, 0, stream>>>(
            f1[lvl], wT + BT1, b1, part, nullptr, 0);

        for (int n0 = 0; n0 < NIMG; n0 += chunk) {
            int n = chunk;
            sample_kernel<<<cdiv(n * HW, TPB), TPB, 0, stream>>>(
                f2[lvl], coords, bufA, n0, n, h2, w2, inv_scale);
            // conv1 sampled-half + partial, relu: A -> B  (K rows 288..575)
            conv_km<32, 96, 48, 64, 48, 64, 1, true, true><<<dim3(12, 6, n), TPB, 0, stream>>>(
                bufA, wT + BT1 + 288 * OC1, b1, bufB, part, n0);
            // conv2 96->128 s2 relu: B -> A
            conv_km<96, 128, 48, 64, 24, 32, 2, true, false><<<dim3(3, 8, n), TPB, 0, stream>>>(
                bufB, wT + BT2, b2, bufA, nullptr, 0);
            // conv3 128->128 relu: A -> B
            conv_km<128, 128, 24, 32, 24, 32, 1, true, false><<<dim3(3, 8, n), TPB, 0, stream>>>(
                bufA, wT + BT3, b3, bufB, nullptr, 0);
            // conv4 128->64 relu: B -> A
            conv_km<128, 64, 24, 32, 24, 32, 1, true, false><<<dim3(3, 4, n), TPB, 0, stream>>>(
                bufB, wT + BT4, b4, bufA, nullptr, 0);
            // deconv 64->32 relu: A -> B
            deconv_km<<<dim3(3, 8, n), TPB, 0, stream>>>(bufA, wT + BT5, b5, bufB);
            // conv6 32->1: B -> cost
            conv6_kernel<<<cdiv(n * HW, TPB), TPB, 0, stream>>>(bufB, w6, b6, cost, n0, n);
        }
        dap_kernel<<<cdiv(NB * 81 * HW, TPB), TPB, 0, stream>>>(
            cost, dapw + (size_t)lvl * 81 * 81, out, lvl);
    }
}

// Round 10
// 2891.048 us; speedup vs baseline: 7.7956x; 2.6945x over previous
//
#include <hip/hip_runtime.h>

// ---------------------------------------------------------------------------
// RAFT+DICL correlation module — fp16 MFMA implicit-GEMM matching net, v4.
//  - activations NHWC fp16; weights prepacked into mfma_f32_16x16x32_f16
//    B-fragments (per 3x3-tap, per 32-ic step). fp32 accumulate.
//  - conv1 split kept: f1-half fp32 (part) feeds MFMA C-in.
//  - deconv = 4 parity classes of 2x2-tap MFMA convs.
//  - sample/conv6/DAP stay fp32-math (conv6 reads fp16).
// Input order INTERLEAVED: d_in[0]=fmap1_0, d_in[1]=fmap2_0, ...
// ---------------------------------------------------------------------------

typedef _Float16 half_t;
typedef _Float16 f16x8 __attribute__((ext_vector_type(8)));
typedef float f32x4 __attribute__((ext_vector_type(4)));

constexpr int D9 = 9, NB = 2, HH = 48, WW = 64;
constexpr int NIMG = NB * D9 * D9;   // 162
constexpr int HW = HH * WW;          // 3072
constexpr int H2 = 24, W2 = 32, HW2 = H2 * W2;

// fragment array sizes (halves) per level: [tap][s][octile][lane*8+j]
constexpr int F1S = 9 * 1 * 6 * 512;     // conv1 sampled-half: IC 32..63, OC 96
constexpr int F2S = 9 * 3 * 8 * 512;     // conv2
constexpr int F3S = 9 * 4 * 8 * 512;     // conv3
constexpr int F4S = 9 * 4 * 4 * 512;     // conv4
constexpr int F5S = 4 * 4 * 2 * 2 * 512; // deconv: [cls][uv][s][tile]
constexpr int KT1 = 576, WT1L = KT1 * 96; // K-major fp32 conv1 weights (full)

static inline int cdiv(int a, int b) { return (a + b - 1) / b; }

// ---------------- weight prep ----------------
__global__ void transpose_w(const float* __restrict__ w, float* __restrict__ wT,
                            int OC, int K, int dstStride)
{
    int idx = blockIdx.x * blockDim.x + threadIdx.x;
    int tot = 4 * OC * K;
    if (idx >= tot) return;
    int lvl = idx / (OC * K);
    int r = idx - lvl * OC * K;
    int oc = r / K;
    int k = r - oc * K;
    wT[(size_t)lvl * dstStride + (size_t)k * OC + oc] = w[idx];
}

// 3x3 conv weights OIHW fp32 -> B-frag fp16 [lvl][t][s][tile][lane*8+j]
template <int OC, int ICSRC, int ICBASE, int ICS>
__global__ void prep3(const float* __restrict__ w, half_t* __restrict__ dst)
{
    constexpr int NT = OC / 16;
    constexpr int LS = 9 * ICS * NT * 512;
    int idx = blockIdx.x * blockDim.x + threadIdx.x;
    if (idx >= 4 * LS) return;
    int j = idx & 7, l = (idx >> 3) & 63;
    int r = idx >> 9;
    int tile = r % NT; r /= NT;
    int s = r % ICS;  r /= ICS;
    int t = r % 9;    r /= 9;
    int lvl = r;
    int ic = ICBASE + s * 32 + (l >> 4) * 8 + j;
    int oc = tile * 16 + (l & 15);
    float v = w[(size_t)lvl * OC * ICSRC * 9 + ((size_t)oc * ICSRC + ic) * 9 + t];
    dst[(size_t)lvl * LS + (((t * ICS + s) * NT + tile) << 9) + l * 8 + j] = (half_t)v;
}

// deconv weights [lvl][oc=32][ic=64][4][4] -> frags [lvl][cls][uv*2+s][tile][512]
__global__ void prep5(const float* __restrict__ w, half_t* __restrict__ dst)
{
    constexpr int LS = F5S;
    int idx = blockIdx.x * blockDim.x + threadIdx.x;
    if (idx >= 4 * LS) return;
    int j = idx & 7, l = (idx >> 3) & 63;
    int r = idx >> 9;
    int tile = r & 1; r >>= 1;
    int s = r & 1;    r >>= 1;
    int uv = r & 3;   r >>= 2;
    int cls = r & 3;  r >>= 2;
    int lvl = r;
    int u = uv >> 1, v = uv & 1, p = cls >> 1, q = cls & 1;
    int ky = p + 2 * u, kx = q + 2 * v;
    int ic = s * 32 + (l >> 4) * 8 + j;
    int oc = tile * 16 + (l & 15);
    float val = w[(size_t)lvl * 32 * 64 * 16 + ((size_t)oc * 64 + ic) * 16 + ky * 4 + kx];
    dst[(size_t)lvl * LS + (((cls * 8 + uv * 2 + s) * 2 + tile) << 9) + l * 8 + j] = (half_t)val;
}

// ---------------- conv1 f1-half (fp32, NHWC fp32 out), 2 images ----------------
__global__ __launch_bounds__(256)
void conv_part(const float* __restrict__ in, const float* __restrict__ wT,
               const float* __restrict__ bias, float* __restrict__ out)
{
    constexpr int TO = 16, IC = 32, OC = 96;
    int tx = threadIdx.x;
    int ox = tx % WW;
    int oy = blockIdx.x * 4 + tx / WW;
    int oc0 = blockIdx.y * TO;
    int n = blockIdx.z;

    float acc[TO];
    #pragma unroll
    for (int o = 0; o < TO; ++o) acc[o] = bias[oc0 + o];
    bool mL = ox >= 1, mR = ox + 1 < WW;
    int xl = mL ? ox - 1 : 0, xr = mR ? ox + 1 : WW - 1;
    const float* ip = in + (size_t)n * IC * HW;
    const float* wk = wT + oc0;
    for (int ic = 0; ic < IC; ++ic) {
        const float* icp = ip + ic * HW;
        const float* wpk = wk + ic * 9 * OC;
        #pragma unroll
        for (int ky = 0; ky < 3; ++ky) {
            int iy = oy + ky - 1;
            if ((unsigned)iy < (unsigned)HH) {
                const float* rp = icp + iy * WW;
                float v0 = rp[xl]; v0 = mL ? v0 : 0.f;
                float v1 = rp[ox];
                float v2 = rp[xr]; v2 = mR ? v2 : 0.f;
                const float* wp = wpk + ky * 3 * OC;
                #pragma unroll
                for (int o = 0; o < TO; ++o) acc[o] = fmaf(v0, wp[o], acc[o]);
                #pragma unroll
                for (int o = 0; o < TO; ++o) acc[o] = fmaf(v1, wp[OC + o], acc[o]);
                #pragma unroll
                for (int o = 0; o < TO; ++o) acc[o] = fmaf(v2, wp[2 * OC + o], acc[o]);
            }
        }
    }
    float* ob = out + ((size_t)n * HW + oy * WW + ox) * OC + oc0;
    #pragma unroll
    for (int o = 0; o < TO; ++o) ob[o] = acc[o];   // no relu (pre-activation partial)
}

// ---------------- sampling -> corr NHWC fp16 (sampled 32 ch) ----------------
__global__ void sample_kernel(const float* __restrict__ f2,
                              const float* __restrict__ coords, half_t* __restrict__ corr,
                              int n0, int nimg, int h2, int w2, float inv_scale)
{
    int idx = blockIdx.x * blockDim.x + threadIdx.x;
    if (idx >= nimg * HW) return;
    int x = idx % WW;
    int t = idx / WW;
    int y = t % HH;
    int nl = t / HH;
    int ng = n0 + nl;
    int b = ng / 81;
    int c81 = ng % 81;
    int di = c81 / D9, dj = c81 % D9;

    float cx = coords[((size_t)(b * 2 + 0) * HH + y) * WW + x];
    float cy = coords[((size_t)(b * 2 + 1) * HH + y) * WW + x];
    float gx = cx * inv_scale + (float)(di - 4);
    float gy = cy * inv_scale + (float)(dj - 4);
    float x0f = floorf(gx), y0f = floorf(gy);
    float wx = gx - x0f, wy = gy - y0f;
    int x0 = (int)x0f, y0 = (int)y0f;
    int x1 = x0 + 1, y1 = y0 + 1;
    bool vx0 = (x0 >= 0) && (x0 <= w2 - 1), vx1 = (x1 >= 0) && (x1 <= w2 - 1);
    bool vy0 = (y0 >= 0) && (y0 <= h2 - 1), vy1 = (y1 >= 0) && (y1 <= h2 - 1);
    int xc0 = min(max(x0, 0), w2 - 1), xc1 = min(max(x1, 0), w2 - 1);
    int yc0 = min(max(y0, 0), h2 - 1), yc1 = min(max(y1, 0), h2 - 1);
    float m00 = (vx0 && vy0) ? (1.f - wx) * (1.f - wy) : 0.f;
    float m10 = (vx1 && vy0) ? wx * (1.f - wy) : 0.f;
    float m01 = (vx0 && vy1) ? (1.f - wx) * wy : 0.f;
    float m11 = (vx1 && vy1) ? wx * wy : 0.f;

    const float* f2b = f2 + (size_t)b * 32 * h2 * w2;
    half_t* outb = corr + ((size_t)nl * HW + y * WW + x) * 32;
    int o00 = yc0 * w2 + xc0, o10 = yc0 * w2 + xc1;
    int o01 = yc1 * w2 + xc0, o11 = yc1 * w2 + xc1;
    #pragma unroll 8
    for (int ch = 0; ch < 32; ++ch) {
        const float* im = f2b + (size_t)ch * h2 * w2;
        float v = m00 * im[o00] + m10 * im[o10] + m01 * im[o01] + m11 * im[o11];
        outb[ch] = (half_t)v;
    }
}

// ---------------- MFMA 3x3 conv (NHWC fp16 in/out) ----------------
// wave: 4 px-tiles x 2 oc-tiles; K split per tap into 32-ic MFMA steps.
template <int ICS, int ICT, int OC, int IH, int IW, int OH, int OW, int S, bool PARTI>
__global__ __launch_bounds__(256)
void conv_mfma(const half_t* __restrict__ in, const half_t* __restrict__ wfrag,
               const float* __restrict__ bias, half_t* __restrict__ out,
               const float* __restrict__ part, int n0)
{
    constexpr int NT = OC / 16;
    int lane = threadIdx.x & 63;
    int wv = threadIdx.x >> 6;
    int n = blockIdx.z;
    int tile0 = blockIdx.y * 2;             // oc tile pair
    int pt0 = blockIdx.x * 16 + wv * 4;     // first px-tile of this wave
    int colc = lane & 15;                   // A-row / C-col
    int kg = lane >> 4;                     // k-group / C-row-group

    const half_t* inn = in + (size_t)n * IH * IW * ICT;

    int px[4], py[4];
    #pragma unroll
    for (int m = 0; m < 4; ++m) {
        int p = (pt0 + m) * 16 + colc;
        px[m] = p % OW;
        py[m] = p / OW;
    }

    f32x4 acc[4][2];
    if (PARTI) {
        int bimg = (n0 + n) / 81;
        const float* pp = part + (size_t)bimg * OH * OW * 96;
        #pragma unroll
        for (int m = 0; m < 4; ++m)
            #pragma unroll
            for (int nn = 0; nn < 2; ++nn)
                #pragma unroll
                for (int j = 0; j < 4; ++j)
                    acc[m][nn][j] = pp[(size_t)((pt0 + m) * 16 + kg * 4 + j) * 96
                                       + (tile0 + nn) * 16 + colc];
    } else {
        float b0 = bias[tile0 * 16 + colc];
        float b1 = bias[tile0 * 16 + 16 + colc];
        #pragma unroll
        for (int m = 0; m < 4; ++m)
            #pragma unroll
            for (int j = 0; j < 4; ++j) { acc[m][0][j] = b0; acc[m][1][j] = b1; }
    }

    f16x8 zz = {};
    #pragma unroll
    for (int t = 0; t < 9; ++t) {
        int dy = t / 3 - 1, dx = t % 3 - 1;
        const half_t* ap[4];
        bool av[4];
        #pragma unroll
        for (int m = 0; m < 4; ++m) {
            int sx = px[m] * S + dx, sy = py[m] * S + dy;
            av[m] = ((unsigned)sx < (unsigned)IW) && ((unsigned)sy < (unsigned)IH);
            int sxc = min(max(sx, 0), IW - 1), syc = min(max(sy, 0), IH - 1);
            ap[m] = inn + ((size_t)syc * IW + sxc) * ICT + kg * 8;
        }
        #pragma unroll
        for (int s = 0; s < ICS; ++s) {
            f16x8 b0v = *(const f16x8*)(wfrag + (((t * ICS + s) * NT + tile0) << 9) + lane * 8);
            f16x8 b1v = *(const f16x8*)(wfrag + (((t * ICS + s) * NT + tile0 + 1) << 9) + lane * 8);
            #pragma unroll
            for (int m = 0; m < 4; ++m) {
                f16x8 a = *(const f16x8*)(ap[m] + s * 32);
                a = av[m] ? a : zz;
                acc[m][0] = __builtin_amdgcn_mfma_f32_16x16x32_f16(a, b0v, acc[m][0], 0, 0, 0);
                acc[m][1] = __builtin_amdgcn_mfma_f32_16x16x32_f16(a, b1v, acc[m][1], 0, 0, 0);
            }
        }
    }

    #pragma unroll
    for (int m = 0; m < 4; ++m)
        #pragma unroll
        for (int nn = 0; nn < 2; ++nn)
            #pragma unroll
            for (int j = 0; j < 4; ++j) {
                float r = fmaxf(acc[m][nn][j], 0.f);   // all MFMA convs are relu'd
                int p = (pt0 + m) * 16 + kg * 4 + j;
                out[((size_t)n * OH * OW + p) * OC + (tile0 + nn) * 16 + colc] = (half_t)r;
            }
}

// ---------------- MFMA deconv (4 parity classes) ----------------
__global__ __launch_bounds__(256)
void deconv_mfma(const half_t* __restrict__ in, const half_t* __restrict__ wfrag,
                 const float* __restrict__ bias, half_t* __restrict__ out)
{
    int lane = threadIdx.x & 63;
    int wv = threadIdx.x >> 6;
    int n = blockIdx.z;
    int cls = blockIdx.y;
    int p = cls >> 1, q = cls & 1;
    int pt0 = blockIdx.x * 16 + wv * 4;
    int colc = lane & 15, kg = lane >> 4;
    const half_t* inn = in + (size_t)n * HW2 * 64;

    int pa[4], pb[4];
    #pragma unroll
    for (int m = 0; m < 4; ++m) {
        int pos = (pt0 + m) * 16 + colc;
        pa[m] = pos >> 5;
        pb[m] = pos & 31;
    }

    f32x4 acc[4][2];
    float b0 = bias[colc], b1 = bias[16 + colc];
    #pragma unroll
    for (int m = 0; m < 4; ++m)
        #pragma unroll
        for (int j = 0; j < 4; ++j) { acc[m][0][j] = b0; acc[m][1][j] = b1; }

    f16x8 zz = {};
    #pragma unroll
    for (int uv = 0; uv < 4; ++uv) {
        int u = uv >> 1, v = uv & 1;
        const half_t* ap[4];
        bool av[4];
        #pragma unroll
        for (int m = 0; m < 4; ++m) {
            int sy = pa[m] + p - 1 + u, sx = pb[m] + q - 1 + v;
            av[m] = ((unsigned)sx < (unsigned)W2) && ((unsigned)sy < (unsigned)H2);
            int sxc = min(max(sx, 0), W2 - 1), syc = min(max(sy, 0), H2 - 1);
            ap[m] = inn + ((size_t)syc * W2 + sxc) * 64 + kg * 8;
        }
        #pragma unroll
        for (int s = 0; s < 2; ++s) {
            f16x8 b0v = *(const f16x8*)(wfrag + (((cls * 8 + uv * 2 + s) * 2 + 0) << 9) + lane * 8);
            f16x8 b1v = *(const f16x8*)(wfrag + (((cls * 8 + uv * 2 + s) * 2 + 1) << 9) + lane * 8);
            #pragma unroll
            for (int m = 0; m < 4; ++m) {
                f16x8 a = *(const f16x8*)(ap[m] + s * 32);
                a = av[m] ? a : zz;
                acc[m][0] = __builtin_amdgcn_mfma_f32_16x16x32_f16(a, b0v, acc[m][0], 0, 0, 0);
                acc[m][1] = __builtin_amdgcn_mfma_f32_16x16x32_f16(a, b1v, acc[m][1], 0, 0, 0);
            }
        }
    }

    #pragma unroll
    for (int m = 0; m < 4; ++m)
        #pragma unroll
        for (int nn = 0; nn < 2; ++nn)
            #pragma unroll
            for (int j = 0; j < 4; ++j) {
                int pos = (pt0 + m) * 16 + kg * 4 + j;
                int a2 = pos >> 5, b2 = pos & 31;
                int oy = 2 * a2 + p, ox = 2 * b2 + q;
                float r = fmaxf(acc[m][nn][j], 0.f);
                out[((size_t)n * HW + oy * WW + ox) * 32 + nn * 16 + colc] = (half_t)r;
            }
}

// ---------------- conv6 (32->1), fp16 NHWC in, fp32 out ----------------
__global__ void conv6_kernel(const half_t* __restrict__ in, const float* __restrict__ w6,
                             const float* __restrict__ b6, float* __restrict__ cost,
                             int n0, int nimg)
{
    int idx = blockIdx.x * blockDim.x + threadIdx.x;
    if (idx >= nimg * HW) return;
    int x = idx % WW;
    int t = idx / WW;
    int y = t % HH;
    int nl = t / HH;
    float acc = b6[0];
    const half_t* ib = in + (size_t)nl * HW * 32;
    #pragma unroll
    for (int tap = 0; tap < 9; ++tap) {
        int sy = y + tap / 3 - 1, sx = x + tap % 3 - 1;
        if ((unsigned)sy < (unsigned)HH && (unsigned)sx < (unsigned)WW) {
            const half_t* pp = ib + ((size_t)sy * WW + sx) * 32;
            #pragma unroll
            for (int ic = 0; ic < 32; ++ic)
                acc = fmaf((float)pp[ic], w6[ic * 9 + tap], acc);
        }
    }
    cost[(size_t)(n0 + nl) * HW + y * WW + x] = acc;
}

// ---------------- DAP ----------------
__global__ void dap_kernel(const float* __restrict__ cost, const float* __restrict__ dapw,
                           float* __restrict__ out, int lvl)
{
    int idx = blockIdx.x * blockDim.x + threadIdx.x;
    if (idx >= NB * 81 * HW) return;
    int px = idx % HW;
    int t = idx / HW;
    int o = t % 81;
    int b = t / 81;
    const float* dw = dapw + (size_t)o * 81;
    const float* cb = cost + (size_t)b * 81 * HW + px;
    float acc = 0.f;
    #pragma unroll 9
    for (int c = 0; c < 81; ++c) acc = fmaf(dw[c], cb[(size_t)c * HW], acc);
    out[((size_t)(b * 4 * 81 + lvl * 81 + o)) * HW + px] = acc;
}

// ---------------------------------------------------------------------------
extern "C" void kernel_launch(void* const* d_in, const int* in_sizes, int n_in,
                              void* d_out, int out_size, void* d_ws, size_t ws_size,
                              hipStream_t stream)
{
    const float* f1[4] = {(const float*)d_in[0], (const float*)d_in[2],
                          (const float*)d_in[4], (const float*)d_in[6]};
    const float* f2[4] = {(const float*)d_in[1], (const float*)d_in[3],
                          (const float*)d_in[5], (const float*)d_in[7]};
    const float* coords = (const float*)d_in[8];
    const float* mw1 = (const float*)d_in[9];
    const float* mb1 = (const float*)d_in[10];
    const float* mw2 = (const float*)d_in[11];
    const float* mb2 = (const float*)d_in[12];
    const float* mw3 = (const float*)d_in[13];
    const float* mb3 = (const float*)d_in[14];
    const float* mw4 = (const float*)d_in[15];
    const float* mb4 = (const float*)d_in[16];
    const float* mw5 = (const float*)d_in[17];
    const float* mb5 = (const float*)d_in[18];
    const float* mw6 = (const float*)d_in[19];
    const float* mb6 = (const float*)d_in[20];
    const float* dapw = (const float*)d_in[21];
    float* out = (float*)d_out;

    auto al = [](size_t x) { return (x + 255) / 256 * 256; };
    // ws: wT1(f32) | frags(f16) | part(f32) | cost(f32) | bufA(f16) | bufB(f16)
    const size_t wT1B = al((size_t)4 * WT1L * 4);
    const size_t fragB = al((size_t)4 * (F1S + F2S + F3S + F4S + F5S) * 2);
    const size_t partB = al((size_t)NB * HW * 96 * 4);
    const size_t costB = al((size_t)NIMG * HW * 4);
    const size_t SA = (size_t)HW * 32 * 2;   // corr / x2(768*128*2) / x4 — max 196608
    const size_t SB = (size_t)HW * 96 * 2;   // x1 / x3 / x5 — max 589824

    static const int divs[10] = {162, 81, 54, 27, 18, 9, 6, 3, 2, 1};
    int chunk = 1;
    for (int i = 0; i < 10; ++i) {
        size_t need = wT1B + fragB + partB + costB + (size_t)divs[i] * (SA + SB) + 1024;
        if (need <= ws_size) { chunk = divs[i]; break; }
    }

    char* wsb = (char*)d_ws;
    float* wT1 = (float*)wsb;
    half_t* frags = (half_t*)(wsb + wT1B);
    half_t* Fr1 = frags;
    half_t* Fr2 = Fr1 + (size_t)4 * F1S;
    half_t* Fr3 = Fr2 + (size_t)4 * F2S;
    half_t* Fr4 = Fr3 + (size_t)4 * F3S;
    half_t* Fr5 = Fr4 + (size_t)4 * F4S;
    float* part = (float*)(wsb + wT1B + fragB);
    float* cost = (float*)(wsb + wT1B + fragB + partB);
    half_t* bufA = (half_t*)(wsb + wT1B + fragB + partB + costB);
    half_t* bufB = (half_t*)(wsb + wT1B + fragB + partB + costB + (size_t)chunk * SA);

    const int TPB = 256;

    transpose_w<<<cdiv(4 * 96 * KT1, TPB), TPB, 0, stream>>>(mw1, wT1, 96, KT1, WT1L);
    prep3<96, 64, 32, 1><<<cdiv(4 * F1S, TPB), TPB, 0, stream>>>(mw1, Fr1);
    prep3<128, 96, 0, 3><<<cdiv(4 * F2S, TPB), TPB, 0, stream>>>(mw2, Fr2);
    prep3<128, 128, 0, 4><<<cdiv(4 * F3S, TPB), TPB, 0, stream>>>(mw3, Fr3);
    prep3<64, 128, 0, 4><<<cdiv(4 * F4S, TPB), TPB, 0, stream>>>(mw4, Fr4);
    prep5<<<cdiv(4 * F5S, TPB), TPB, 0, stream>>>(mw5, Fr5);

    for (int lvl = 0; lvl < 4; ++lvl) {
        int h2 = HH >> lvl, w2 = WW >> lvl;
        float inv_scale = 1.0f / (float)(1 << lvl);
        const float* b1 = mb1 + (size_t)lvl * 96;
        const float* b2 = mb2 + (size_t)lvl * 128;
        const float* b3 = mb3 + (size_t)lvl * 128;
        const float* b4 = mb4 + (size_t)lvl * 64;
        const float* b5 = mb5 + (size_t)lvl * 32;
        const float* w6 = mw6 + (size_t)lvl * 288;
        const float* b6 = mb6 + (size_t)lvl * 1;

        // conv1 f1-half (fp32, NHWC, bias, no relu) for the 2 batch images
        conv_part<<<dim3(12, 6, 2), TPB, 0, stream>>>(f1[lvl], wT1 + (size_t)lvl * WT1L, b1, part);

        for (int n0 = 0; n0 < NIMG; n0 += chunk) {
            int n = chunk;
            sample_kernel<<<cdiv(n * HW, TPB), TPB, 0, stream>>>(
                f2[lvl], coords, bufA, n0, n, h2, w2, inv_scale);
            // conv1 sampled-half MFMA + part C-init, relu: A -> B
            conv_mfma<1, 32, 96, 48, 64, 48, 64, 1, true><<<dim3(12, 3, n), TPB, 0, stream>>>(
                bufA, Fr1 + (size_t)lvl * F1S, b1, bufB, part, n0);
            // conv2 96->128 s2 relu: B -> A
            conv_mfma<3, 96, 128, 48, 64, 24, 32, 2, false><<<dim3(3, 4, n), TPB, 0, stream>>>(
                bufB, Fr2 + (size_t)lvl * F2S, b2, bufA, nullptr, 0);
            // conv3 128->128 relu: A -> B
            conv_mfma<4, 128, 128, 24, 32, 24, 32, 1, false><<<dim3(3, 4, n), TPB, 0, stream>>>(
                bufA, Fr3 + (size_t)lvl * F3S, b3, bufB, nullptr, 0);
            // conv4 128->64 relu: B -> A
            conv_mfma<4, 128, 64, 24, 32, 24, 32, 1, false><<<dim3(3, 2, n), TPB, 0, stream>>>(
                bufB, Fr4 + (size_t)lvl * F4S, b4, bufA, nullptr, 0);
            // deconv 64->32 relu: A -> B
            deconv_mfma<<<dim3(3, 4, n), TPB, 0, stream>>>(bufA, Fr5 + (size_t)lvl * F5S, b5, bufB);
            // conv6 32->1: B -> cost
            conv6_kernel<<<cdiv(n * HW, TPB), TPB, 0, stream>>>(bufB, w6, b6, cost, n0, n);
        }
        dap_kernel<<<cdiv(NB * 81 * HW, TPB), TPB, 0, stream>>>(
            cost, dapw + (size_t)lvl * 81 * 81, out, lvl);
    }
}

// Round 11
// 1907.905 us; speedup vs baseline: 11.8127x; 1.5153x over previous
//
#include <hip/hip_runtime.h>

// ---------------------------------------------------------------------------
// RAFT+DICL correlation module — fp16 MFMA implicit-GEMM, v5.
//  v4 + two memory-locality fixes (conv stages were 14x HBM-refetch bound):
//   - oc-tile merge: each wave computes NTW=3/4 oc-tiles (grid.y halved)
//   - bijective XCD-aware swizzle on flattened 1-D grids, image-major order
//  conv6 fp16 loads vectorized (f16x8).
// Input order INTERLEAVED: d_in[0]=fmap1_0, d_in[1]=fmap2_0, ...
// ---------------------------------------------------------------------------

typedef _Float16 half_t;
typedef _Float16 f16x8 __attribute__((ext_vector_type(8)));
typedef float f32x4 __attribute__((ext_vector_type(4)));

constexpr int D9 = 9, NB = 2, HH = 48, WW = 64;
constexpr int NIMG = NB * D9 * D9;   // 162
constexpr int HW = HH * WW;          // 3072
constexpr int H2 = 24, W2 = 32, HW2 = H2 * W2;

constexpr int F1S = 9 * 1 * 6 * 512;
constexpr int F2S = 9 * 3 * 8 * 512;
constexpr int F3S = 9 * 4 * 8 * 512;
constexpr int F4S = 9 * 4 * 4 * 512;
constexpr int F5S = 4 * 4 * 2 * 2 * 512;
constexpr int KT1 = 576, WT1L = KT1 * 96;

static inline int cdiv(int a, int b) { return (a + b - 1) / b; }

// Bijective XCD swizzle (m204): launched b -> logical, chunking logical space
// so contiguous logical blocks (image-major) stay on one XCD (b%8).
__device__ __forceinline__ int xcd_swz(int b, int nb)
{
    int q = nb >> 3, r = nb & 7;
    int x = b & 7, j = b >> 3;
    return (x < r) ? (x * (q + 1) + j) : (r + x * q + j);
}

// ---------------- weight prep ----------------
__global__ void transpose_w(const float* __restrict__ w, float* __restrict__ wT,
                            int OC, int K, int dstStride)
{
    int idx = blockIdx.x * blockDim.x + threadIdx.x;
    int tot = 4 * OC * K;
    if (idx >= tot) return;
    int lvl = idx / (OC * K);
    int r = idx - lvl * OC * K;
    int oc = r / K;
    int k = r - oc * K;
    wT[(size_t)lvl * dstStride + (size_t)k * OC + oc] = w[idx];
}

template <int OC, int ICSRC, int ICBASE, int ICS>
__global__ void prep3(const float* __restrict__ w, half_t* __restrict__ dst)
{
    constexpr int NT = OC / 16;
    constexpr int LS = 9 * ICS * NT * 512;
    int idx = blockIdx.x * blockDim.x + threadIdx.x;
    if (idx >= 4 * LS) return;
    int j = idx & 7, l = (idx >> 3) & 63;
    int r = idx >> 9;
    int tile = r % NT; r /= NT;
    int s = r % ICS;  r /= ICS;
    int t = r % 9;    r /= 9;
    int lvl = r;
    int ic = ICBASE + s * 32 + (l >> 4) * 8 + j;
    int oc = tile * 16 + (l & 15);
    float v = w[(size_t)lvl * OC * ICSRC * 9 + ((size_t)oc * ICSRC + ic) * 9 + t];
    dst[(size_t)lvl * LS + (((t * ICS + s) * NT + tile) << 9) + l * 8 + j] = (half_t)v;
}

__global__ void prep5(const float* __restrict__ w, half_t* __restrict__ dst)
{
    constexpr int LS = F5S;
    int idx = blockIdx.x * blockDim.x + threadIdx.x;
    if (idx >= 4 * LS) return;
    int j = idx & 7, l = (idx >> 3) & 63;
    int r = idx >> 9;
    int tile = r & 1; r >>= 1;
    int s = r & 1;    r >>= 1;
    int uv = r & 3;   r >>= 2;
    int cls = r & 3;  r >>= 2;
    int lvl = r;
    int u = uv >> 1, v = uv & 1, p = cls >> 1, q = cls & 1;
    int ky = p + 2 * u, kx = q + 2 * v;
    int ic = s * 32 + (l >> 4) * 8 + j;
    int oc = tile * 16 + (l & 15);
    float val = w[(size_t)lvl * 32 * 64 * 16 + ((size_t)oc * 64 + ic) * 16 + ky * 4 + kx];
    dst[(size_t)lvl * LS + (((cls * 8 + uv * 2 + s) * 2 + tile) << 9) + l * 8 + j] = (half_t)val;
}

// ---------------- conv1 f1-half (fp32, NHWC fp32 out), 2 images ----------------
__global__ __launch_bounds__(256)
void conv_part(const float* __restrict__ in, const float* __restrict__ wT,
               const float* __restrict__ bias, float* __restrict__ out)
{
    constexpr int TO = 16, IC = 32, OC = 96;
    int tx = threadIdx.x;
    int ox = tx % WW;
    int oy = blockIdx.x * 4 + tx / WW;
    int oc0 = blockIdx.y * TO;
    int n = blockIdx.z;

    float acc[TO];
    #pragma unroll
    for (int o = 0; o < TO; ++o) acc[o] = bias[oc0 + o];
    bool mL = ox >= 1, mR = ox + 1 < WW;
    int xl = mL ? ox - 1 : 0, xr = mR ? ox + 1 : WW - 1;
    const float* ip = in + (size_t)n * IC * HW;
    const float* wk = wT + oc0;
    for (int ic = 0; ic < IC; ++ic) {
        const float* icp = ip + ic * HW;
        const float* wpk = wk + ic * 9 * OC;
        #pragma unroll
        for (int ky = 0; ky < 3; ++ky) {
            int iy = oy + ky - 1;
            if ((unsigned)iy < (unsigned)HH) {
                const float* rp = icp + iy * WW;
                float v0 = rp[xl]; v0 = mL ? v0 : 0.f;
                float v1 = rp[ox];
                float v2 = rp[xr]; v2 = mR ? v2 : 0.f;
                const float* wp = wpk + ky * 3 * OC;
                #pragma unroll
                for (int o = 0; o < TO; ++o) acc[o] = fmaf(v0, wp[o], acc[o]);
                #pragma unroll
                for (int o = 0; o < TO; ++o) acc[o] = fmaf(v1, wp[OC + o], acc[o]);
                #pragma unroll
                for (int o = 0; o < TO; ++o) acc[o] = fmaf(v2, wp[2 * OC + o], acc[o]);
            }
        }
    }
    float* ob = out + ((size_t)n * HW + oy * WW + ox) * OC + oc0;
    #pragma unroll
    for (int o = 0; o < TO; ++o) ob[o] = acc[o];
}

// ---------------- sampling -> corr NHWC fp16 ----------------
__global__ void sample_kernel(const float* __restrict__ f2,
                              const float* __restrict__ coords, half_t* __restrict__ corr,
                              int n0, int nimg, int h2, int w2, float inv_scale)
{
    int idx = blockIdx.x * blockDim.x + threadIdx.x;
    if (idx >= nimg * HW) return;
    int x = idx % WW;
    int t = idx / WW;
    int y = t % HH;
    int nl = t / HH;
    int ng = n0 + nl;
    int b = ng / 81;
    int c81 = ng % 81;
    int di = c81 / D9, dj = c81 % D9;

    float cx = coords[((size_t)(b * 2 + 0) * HH + y) * WW + x];
    float cy = coords[((size_t)(b * 2 + 1) * HH + y) * WW + x];
    float gx = cx * inv_scale + (float)(di - 4);
    float gy = cy * inv_scale + (float)(dj - 4);
    float x0f = floorf(gx), y0f = floorf(gy);
    float wx = gx - x0f, wy = gy - y0f;
    int x0 = (int)x0f, y0 = (int)y0f;
    int x1 = x0 + 1, y1 = y0 + 1;
    bool vx0 = (x0 >= 0) && (x0 <= w2 - 1), vx1 = (x1 >= 0) && (x1 <= w2 - 1);
    bool vy0 = (y0 >= 0) && (y0 <= h2 - 1), vy1 = (y1 >= 0) && (y1 <= h2 - 1);
    int xc0 = min(max(x0, 0), w2 - 1), xc1 = min(max(x1, 0), w2 - 1);
    int yc0 = min(max(y0, 0), h2 - 1), yc1 = min(max(y1, 0), h2 - 1);
    float m00 = (vx0 && vy0) ? (1.f - wx) * (1.f - wy) : 0.f;
    float m10 = (vx1 && vy0) ? wx * (1.f - wy) : 0.f;
    float m01 = (vx0 && vy1) ? (1.f - wx) * wy : 0.f;
    float m11 = (vx1 && vy1) ? wx * wy : 0.f;

    const float* f2b = f2 + (size_t)b * 32 * h2 * w2;
    half_t* outb = corr + ((size_t)nl * HW + y * WW + x) * 32;
    int o00 = yc0 * w2 + xc0, o10 = yc0 * w2 + xc1;
    int o01 = yc1 * w2 + xc0, o11 = yc1 * w2 + xc1;
    #pragma unroll 8
    for (int ch = 0; ch < 32; ++ch) {
        const float* im = f2b + (size_t)ch * h2 * w2;
        float v = m00 * im[o00] + m10 * im[o10] + m01 * im[o01] + m11 * im[o11];
        outb[ch] = (half_t)v;
    }
}

// ---------------- MFMA 3x3 conv (NHWC fp16), NTW oc-tiles per wave ----------
// 1-D grid, XCD-swizzled, logical order: image-major (n, ty, tx).
template <int ICS, int ICT, int OC, int IH, int IW, int OH, int OW, int S, bool PARTI, int NTW>
__global__ __launch_bounds__(256)
void conv_mfma(const half_t* __restrict__ in, const half_t* __restrict__ wfrag,
               const float* __restrict__ bias, half_t* __restrict__ out,
               const float* __restrict__ part, int n0, int gx, int gxy, int nb)
{
    constexpr int NT = OC / 16;
    int lb = xcd_swz(blockIdx.x, nb);
    int n = lb / gxy;
    int rem = lb - n * gxy;
    int ty = rem / gx;
    int tx = rem - ty * gx;

    int lane = threadIdx.x & 63;
    int wv = threadIdx.x >> 6;
    int tile0 = ty * NTW;
    int pt0 = tx * 16 + wv * 4;
    int colc = lane & 15;
    int kg = lane >> 4;

    const half_t* inn = in + (size_t)n * IH * IW * ICT;

    int px[4], py[4];
    #pragma unroll
    for (int m = 0; m < 4; ++m) {
        int p = (pt0 + m) * 16 + colc;
        px[m] = p % OW;
        py[m] = p / OW;
    }

    f32x4 acc[4][NTW];
    if (PARTI) {
        int bimg = (n0 + n) / 81;
        const float* pp = part + (size_t)bimg * OH * OW * 96;
        #pragma unroll
        for (int m = 0; m < 4; ++m)
            #pragma unroll
            for (int nn = 0; nn < NTW; ++nn)
                #pragma unroll
                for (int j = 0; j < 4; ++j)
                    acc[m][nn][j] = pp[(size_t)((pt0 + m) * 16 + kg * 4 + j) * 96
                                       + (tile0 + nn) * 16 + colc];
    } else {
        #pragma unroll
        for (int nn = 0; nn < NTW; ++nn) {
            float bv = bias[(tile0 + nn) * 16 + colc];
            #pragma unroll
            for (int m = 0; m < 4; ++m)
                #pragma unroll
                for (int j = 0; j < 4; ++j) acc[m][nn][j] = bv;
        }
    }

    f16x8 zz = {};
    #pragma unroll
    for (int t = 0; t < 9; ++t) {
        int dy = t / 3 - 1, dx = t % 3 - 1;
        const half_t* ap[4];
        bool av[4];
        #pragma unroll
        for (int m = 0; m < 4; ++m) {
            int sx = px[m] * S + dx, sy = py[m] * S + dy;
            av[m] = ((unsigned)sx < (unsigned)IW) && ((unsigned)sy < (unsigned)IH);
            int sxc = min(max(sx, 0), IW - 1), syc = min(max(sy, 0), IH - 1);
            ap[m] = inn + ((size_t)syc * IW + sxc) * ICT + kg * 8;
        }
        #pragma unroll
        for (int s = 0; s < ICS; ++s) {
            f16x8 bv[NTW];
            #pragma unroll
            for (int nn = 0; nn < NTW; ++nn)
                bv[nn] = *(const f16x8*)(wfrag + (((t * ICS + s) * NT + tile0 + nn) << 9) + lane * 8);
            #pragma unroll
            for (int m = 0; m < 4; ++m) {
                f16x8 a = *(const f16x8*)(ap[m] + s * 32);
                a = av[m] ? a : zz;
                #pragma unroll
                for (int nn = 0; nn < NTW; ++nn)
                    acc[m][nn] = __builtin_amdgcn_mfma_f32_16x16x32_f16(a, bv[nn], acc[m][nn], 0, 0, 0);
            }
        }
    }

    #pragma unroll
    for (int m = 0; m < 4; ++m)
        #pragma unroll
        for (int nn = 0; nn < NTW; ++nn)
            #pragma unroll
            for (int j = 0; j < 4; ++j) {
                float r = fmaxf(acc[m][nn][j], 0.f);
                int p = (pt0 + m) * 16 + kg * 4 + j;
                out[((size_t)n * OH * OW + p) * OC + (tile0 + nn) * 16 + colc] = (half_t)r;
            }
}

// ---------------- MFMA deconv (4 parity classes), XCD-swizzled --------------
__global__ __launch_bounds__(256)
void deconv_mfma(const half_t* __restrict__ in, const half_t* __restrict__ wfrag,
                 const float* __restrict__ bias, half_t* __restrict__ out, int nb)
{
    int lb = xcd_swz(blockIdx.x, nb);
    int n = lb / 12;
    int rem = lb - n * 12;
    int cls = rem / 3;
    int tx = rem - cls * 3;

    int lane = threadIdx.x & 63;
    int wv = threadIdx.x >> 6;
    int p = cls >> 1, q = cls & 1;
    int pt0 = tx * 16 + wv * 4;
    int colc = lane & 15, kg = lane >> 4;
    const half_t* inn = in + (size_t)n * HW2 * 64;

    int pa[4], pb[4];
    #pragma unroll
    for (int m = 0; m < 4; ++m) {
        int pos = (pt0 + m) * 16 + colc;
        pa[m] = pos >> 5;
        pb[m] = pos & 31;
    }

    f32x4 acc[4][2];
    float b0 = bias[colc], b1 = bias[16 + colc];
    #pragma unroll
    for (int m = 0; m < 4; ++m)
        #pragma unroll
        for (int j = 0; j < 4; ++j) { acc[m][0][j] = b0; acc[m][1][j] = b1; }

    f16x8 zz = {};
    #pragma unroll
    for (int uv = 0; uv < 4; ++uv) {
        int u = uv >> 1, v = uv & 1;
        const half_t* ap[4];
        bool av[4];
        #pragma unroll
        for (int m = 0; m < 4; ++m) {
            int sy = pa[m] + p - 1 + u, sx = pb[m] + q - 1 + v;
            av[m] = ((unsigned)sx < (unsigned)W2) && ((unsigned)sy < (unsigned)H2);
            int sxc = min(max(sx, 0), W2 - 1), syc = min(max(sy, 0), H2 - 1);
            ap[m] = inn + ((size_t)syc * W2 + sxc) * 64 + kg * 8;
        }
        #pragma unroll
        for (int s = 0; s < 2; ++s) {
            f16x8 b0v = *(const f16x8*)(wfrag + (((cls * 8 + uv * 2 + s) * 2 + 0) << 9) + lane * 8);
            f16x8 b1v = *(const f16x8*)(wfrag + (((cls * 8 + uv * 2 + s) * 2 + 1) << 9) + lane * 8);
            #pragma unroll
            for (int m = 0; m < 4; ++m) {
                f16x8 a = *(const f16x8*)(ap[m] + s * 32);
                a = av[m] ? a : zz;
                acc[m][0] = __builtin_amdgcn_mfma_f32_16x16x32_f16(a, b0v, acc[m][0], 0, 0, 0);
                acc[m][1] = __builtin_amdgcn_mfma_f32_16x16x32_f16(a, b1v, acc[m][1], 0, 0, 0);
            }
        }
    }

    #pragma unroll
    for (int m = 0; m < 4; ++m)
        #pragma unroll
        for (int nn = 0; nn < 2; ++nn)
            #pragma unroll
            for (int j = 0; j < 4; ++j) {
                int pos = (pt0 + m) * 16 + kg * 4 + j;
                int a2 = pos >> 5, b2 = pos & 31;
                int oy = 2 * a2 + p, ox = 2 * b2 + q;
                float r = fmaxf(acc[m][nn][j], 0.f);
                out[((size_t)n * HW + oy * WW + ox) * 32 + nn * 16 + colc] = (half_t)r;
            }
}

// ---------------- conv6 (32->1), vectorized fp16 reads ----------------
__global__ void conv6_kernel(const half_t* __restrict__ in, const float* __restrict__ w6,
                             const float* __restrict__ b6, float* __restrict__ cost,
                             int n0, int nimg)
{
    int idx = blockIdx.x * blockDim.x + threadIdx.x;
    if (idx >= nimg * HW) return;
    int x = idx % WW;
    int t = idx / WW;
    int y = t % HH;
    int nl = t / HH;
    float acc = b6[0];
    const half_t* ib = in + (size_t)nl * HW * 32;
    #pragma unroll
    for (int tap = 0; tap < 9; ++tap) {
        int sy = y + tap / 3 - 1, sx = x + tap % 3 - 1;
        if ((unsigned)sy < (unsigned)HH && (unsigned)sx < (unsigned)WW) {
            const f16x8* pp = (const f16x8*)(ib + ((size_t)sy * WW + sx) * 32);
            #pragma unroll
            for (int c8 = 0; c8 < 4; ++c8) {
                f16x8 v = pp[c8];
                #pragma unroll
                for (int j = 0; j < 8; ++j)
                    acc = fmaf((float)v[j], w6[(c8 * 8 + j) * 9 + tap], acc);
            }
        }
    }
    cost[(size_t)(n0 + nl) * HW + y * WW + x] = acc;
}

// ---------------- DAP ----------------
__global__ void dap_kernel(const float* __restrict__ cost, const float* __restrict__ dapw,
                           float* __restrict__ out, int lvl)
{
    int idx = blockIdx.x * blockDim.x + threadIdx.x;
    if (idx >= NB * 81 * HW) return;
    int px = idx % HW;
    int t = idx / HW;
    int o = t % 81;
    int b = t / 81;
    const float* dw = dapw + (size_t)o * 81;
    const float* cb = cost + (size_t)b * 81 * HW + px;
    float acc = 0.f;
    #pragma unroll 9
    for (int c = 0; c < 81; ++c) acc = fmaf(dw[c], cb[(size_t)c * HW], acc);
    out[((size_t)(b * 4 * 81 + lvl * 81 + o)) * HW + px] = acc;
}

// ---------------------------------------------------------------------------
extern "C" void kernel_launch(void* const* d_in, const int* in_sizes, int n_in,
                              void* d_out, int out_size, void* d_ws, size_t ws_size,
                              hipStream_t stream)
{
    const float* f1[4] = {(const float*)d_in[0], (const float*)d_in[2],
                          (const float*)d_in[4], (const float*)d_in[6]};
    const float* f2[4] = {(const float*)d_in[1], (const float*)d_in[3],
                          (const float*)d_in[5], (const float*)d_in[7]};
    const float* coords = (const float*)d_in[8];
    const float* mw1 = (const float*)d_in[9];
    const float* mb1 = (const float*)d_in[10];
    const float* mw2 = (const float*)d_in[11];
    const float* mb2 = (const float*)d_in[12];
    const float* mw3 = (const float*)d_in[13];
    const float* mb3 = (const float*)d_in[14];
    const float* mw4 = (const float*)d_in[15];
    const float* mb4 = (const float*)d_in[16];
    const float* mw5 = (const float*)d_in[17];
    const float* mb5 = (const float*)d_in[18];
    const float* mw6 = (const float*)d_in[19];
    const float* mb6 = (const float*)d_in[20];
    const float* dapw = (const float*)d_in[21];
    float* out = (float*)d_out;

    auto al = [](size_t x) { return (x + 255) / 256 * 256; };
    const size_t wT1B = al((size_t)4 * WT1L * 4);
    const size_t fragB = al((size_t)4 * (F1S + F2S + F3S + F4S + F5S) * 2);
    const size_t partB = al((size_t)NB * HW * 96 * 4);
    const size_t costB = al((size_t)NIMG * HW * 4);
    const size_t SA = (size_t)HW * 32 * 2;
    const size_t SB = (size_t)HW * 96 * 2;

    static const int divs[10] = {162, 81, 54, 27, 18, 9, 6, 3, 2, 1};
    int chunk = 1;
    for (int i = 0; i < 10; ++i) {
        size_t need = wT1B + fragB + partB + costB + (size_t)divs[i] * (SA + SB) + 1024;
        if (need <= ws_size) { chunk = divs[i]; break; }
    }

    char* wsb = (char*)d_ws;
    float* wT1 = (float*)wsb;
    half_t* frags = (half_t*)(wsb + wT1B);
    half_t* Fr1 = frags;
    half_t* Fr2 = Fr1 + (size_t)4 * F1S;
    half_t* Fr3 = Fr2 + (size_t)4 * F2S;
    half_t* Fr4 = Fr3 + (size_t)4 * F3S;
    half_t* Fr5 = Fr4 + (size_t)4 * F4S;
    float* part = (float*)(wsb + wT1B + fragB);
    float* cost = (float*)(wsb + wT1B + fragB + partB);
    half_t* bufA = (half_t*)(wsb + wT1B + fragB + partB + costB);
    half_t* bufB = (half_t*)(wsb + wT1B + fragB + partB + costB + (size_t)chunk * SA);

    const int TPB = 256;

    transpose_w<<<cdiv(4 * 96 * KT1, TPB), TPB, 0, stream>>>(mw1, wT1, 96, KT1, WT1L);
    prep3<96, 64, 32, 1><<<cdiv(4 * F1S, TPB), TPB, 0, stream>>>(mw1, Fr1);
    prep3<128, 96, 0, 3><<<cdiv(4 * F2S, TPB), TPB, 0, stream>>>(mw2, Fr2);
    prep3<128, 128, 0, 4><<<cdiv(4 * F3S, TPB), TPB, 0, stream>>>(mw3, Fr3);
    prep3<64, 128, 0, 4><<<cdiv(4 * F4S, TPB), TPB, 0, stream>>>(mw4, Fr4);
    prep5<<<cdiv(4 * F5S, TPB), TPB, 0, stream>>>(mw5, Fr5);

    for (int lvl = 0; lvl < 4; ++lvl) {
        int h2 = HH >> lvl, w2 = WW >> lvl;
        float inv_scale = 1.0f / (float)(1 << lvl);
        const float* b1 = mb1 + (size_t)lvl * 96;
        const float* b2 = mb2 + (size_t)lvl * 128;
        const float* b3 = mb3 + (size_t)lvl * 128;
        const float* b4 = mb4 + (size_t)lvl * 64;
        const float* b5 = mb5 + (size_t)lvl * 32;
        const float* w6 = mw6 + (size_t)lvl * 288;
        const float* b6 = mb6 + (size_t)lvl * 1;

        conv_part<<<dim3(12, 6, 2), TPB, 0, stream>>>(f1[lvl], wT1 + (size_t)lvl * WT1L, b1, part);

        for (int n0 = 0; n0 < NIMG; n0 += chunk) {
            int n = chunk;
            sample_kernel<<<cdiv(n * HW, TPB), TPB, 0, stream>>>(
                f2[lvl], coords, bufA, n0, n, h2, w2, inv_scale);
            // conv1 sampled-half MFMA + part C-init, relu: A -> B  (NT=6, NTW=3, gy=2)
            { int gx = 12, gxy = 24, nb = gxy * n;
              conv_mfma<1, 32, 96, 48, 64, 48, 64, 1, true, 3><<<nb, TPB, 0, stream>>>(
                  bufA, Fr1 + (size_t)lvl * F1S, b1, bufB, part, n0, gx, gxy, nb); }
            // conv2 96->128 s2 relu: B -> A  (NT=8, NTW=4, gy=2)
            { int gx = 3, gxy = 6, nb = gxy * n;
              conv_mfma<3, 96, 128, 48, 64, 24, 32, 2, false, 4><<<nb, TPB, 0, stream>>>(
                  bufB, Fr2 + (size_t)lvl * F2S, b2, bufA, nullptr, 0, gx, gxy, nb); }
            // conv3 128->128 relu: A -> B  (NT=8, NTW=4, gy=2)
            { int gx = 3, gxy = 6, nb = gxy * n;
              conv_mfma<4, 128, 128, 24, 32, 24, 32, 1, false, 4><<<nb, TPB, 0, stream>>>(
                  bufA, Fr3 + (size_t)lvl * F3S, b3, bufB, nullptr, 0, gx, gxy, nb); }
            // conv4 128->64 relu: B -> A  (NT=4, NTW=4, gy=1)
            { int gx = 3, gxy = 3, nb = gxy * n;
              conv_mfma<4, 128, 64, 24, 32, 24, 32, 1, false, 4><<<nb, TPB, 0, stream>>>(
                  bufB, Fr4 + (size_t)lvl * F4S, b4, bufA, nullptr, 0, gx, gxy, nb); }
            // deconv 64->32 relu: A -> B
            { int nb = 12 * n;
              deconv_mfma<<<nb, TPB, 0, stream>>>(bufA, Fr5 + (size_t)lvl * F5S, b5, bufB, nb); }
            // conv6 32->1: B -> cost
            conv6_kernel<<<cdiv(n * HW, TPB), TPB, 0, stream>>>(bufB, w6, b6, cost, n0, n);
        }
        dap_kernel<<<cdiv(NB * 81 * HW, TPB), TPB, 0, stream>>>(
            cost, dapw + (size_t)lvl * 81 * 81, out, lvl);
    }
}